// Round 5
// baseline (632.432 us; speedup 1.0000x reference)
//
#include <hip/hip_runtime.h>
#include <hip/hip_bf16.h>
#include <stdint.h>

// MoE: T=4096 tokens, H=1024, E=8 (top-2), I=2048, IS=4096. fp32 in/out.
// bf16 MFMA (32x32x16) pipeline: one merged transpose dispatch, LDS-staged
// router (also emits bf16 x), merged shared+expert BK=64 GEMMs with
// global_load_lds staging + XOR bank swizzle.

typedef __attribute__((ext_vector_type(8))) short bf16x8;    // MFMA A/B frag
typedef __attribute__((ext_vector_type(16))) float f32x16;   // 32x32 C/D frag
typedef unsigned short u16;

static constexpr int Tt  = 4096;
static constexpr int Hd  = 1024;
static constexpr int NE  = 8;
static constexpr int Id  = 2048;
static constexpr int ISd = 4096;
static constexpr int NR  = Tt * 2;
static constexpr int BM = 128, BN = 128, BN1 = 64, BK = 64;
static constexpr int MAXT = NR / BM + NE;               // 72 worst-case expert M-tiles
static constexpr int G1_SH = (Tt / BM) * (ISd / BN1);   // 2048 shared gemm1 blocks
static constexpr int G1_EX = MAXT * (Id / BN1);         // 2304 expert gemm1 blocks
static constexpr int G2_SH = 8 * (Tt / BM) * 2;         // 512 shared gemm2 (ksplit 2)
static constexpr int G2_EX = 8 * MAXT;                  // 576 expert gemm2

__device__ __forceinline__ u16 f2bf(float f) {  // RNE float->bf16
  union { float f; uint32_t u; } v; v.f = f;
  uint32_t u = v.u;
  u += 0x7fffu + ((u >> 16) & 1u);
  return (u16)(u >> 16);
}

__device__ __forceinline__ void ld16(void* l, const void* g) {
  __builtin_amdgcn_global_load_lds((const __attribute__((address_space(1))) void*)g,
                                   (__attribute__((address_space(3))) void*)l, 16, 0, 0);
}

// ---------------- preprocessing ----------------

// ALL weight transposes in one dispatch. fp32 [z][K][N] -> bf16 [z][N][K], 64x64 tiles.
// Segments: Wg(8z), Wu(8z), Wd(8z), Sg, Su, Sd.
__global__ __launch_bounds__(256)
void k_tcvt(const float* __restrict__ s0, u16* __restrict__ d0,
            const float* __restrict__ s1, u16* __restrict__ d1,
            const float* __restrict__ s2, u16* __restrict__ d2,
            const float* __restrict__ s3, u16* __restrict__ d3,
            const float* __restrict__ s4, u16* __restrict__ d4,
            const float* __restrict__ s5, u16* __restrict__ d5) {
  constexpr int ST[6] = {0, 4096, 8192, 12288, 13312, 14336};
  constexpr int KS[6] = {1024, 1024, 2048, 1024, 1024, 4096};
  constexpr int NS[6] = {2048, 2048, 1024, 4096, 4096, 1024};
  int bid = blockIdx.x;
  int seg = 0;
  #pragma unroll
  for (int i = 1; i < 6; i++) if (bid >= ST[i]) seg = i;
  const float* S; u16* D;
  switch (seg) {
    case 0: S = s0; D = d0; break;
    case 1: S = s1; D = d1; break;
    case 2: S = s2; D = d2; break;
    case 3: S = s3; D = d3; break;
    case 4: S = s4; D = d4; break;
    default: S = s5; D = d5; break;
  }
  int K = KS[seg], N = NS[seg];
  int lb = bid - ST[seg];
  int perz = (N >> 6) * (K >> 6);
  int z = lb / perz, r = lb - z * perz;
  int bx = r % (N >> 6), by = r / (N >> 6);
  S += (size_t)z * K * N; D += (size_t)z * K * N;
  int n0 = bx * 64, k0 = by * 64;

  __shared__ float sm[64][65];
  int tid = threadIdx.x;
  int rr = tid >> 4, cc = (tid & 15) * 4;
  #pragma unroll
  for (int i = 0; i < 4; i++) {
    float4 v = *(const float4*)&S[(size_t)(k0 + i * 16 + rr) * N + n0 + cc];
    sm[i * 16 + rr][cc] = v.x; sm[i * 16 + rr][cc + 1] = v.y;
    sm[i * 16 + rr][cc + 2] = v.z; sm[i * 16 + rr][cc + 3] = v.w;
  }
  __syncthreads();
  int nn = tid >> 3, kc = (tid & 7) * 8;
  #pragma unroll
  for (int i = 0; i < 2; i++) {
    int n = i * 32 + nn;
    union { u16 h[8]; uint4 v; } o;
    #pragma unroll
    for (int t = 0; t < 8; t++) o.h[t] = f2bf(sm[kc + t][n]);
    *(uint4*)&D[(size_t)(n0 + n) * K + k0 + kc] = o.v;
  }
}

// ---------------- router (also casts x -> bf16 xb) ----------------
// 256 blocks x 256 thr. rwm (32 KB) in LDS. 16 thr/token, interleaved float4.

__global__ __launch_bounds__(256)
void k_router(const float* __restrict__ x, const float* __restrict__ rwm,
              u16* __restrict__ xb,
              int* __restrict__ sel, float* __restrict__ wts,
              int* __restrict__ counts) {
  __shared__ float w[NE * Hd];
  __shared__ int lcnt[NE];
  int tid = threadIdx.x;
  if (tid < NE) lcnt[tid] = 0;
  #pragma unroll
  for (int i = 0; i < 8; i++) {
    int idx = (i * 256 + tid) * 4;
    *(float4*)&w[idx] = *(const float4*)&rwm[idx];
  }
  __syncthreads();
  int tok = blockIdx.x * 16 + (tid >> 4);
  int part = tid & 15;
  const float* xt = x + (size_t)tok * Hd;
  u16* xbt = xb + (size_t)tok * Hd;
  float p[NE] = {};
  #pragma unroll
  for (int j = 0; j < 16; j++) {
    int off = j * 64 + part * 4;
    float4 v = *(const float4*)&xt[off];
    ushort4 o;
    o.x = f2bf(v.x); o.y = f2bf(v.y); o.z = f2bf(v.z); o.w = f2bf(v.w);
    *(ushort4*)&xbt[off] = o;
    #pragma unroll
    for (int e = 0; e < NE; e++) {
      float4 wv = *(const float4*)&w[e * Hd + off];
      p[e] += v.x * wv.x + v.y * wv.y + v.z * wv.z + v.w * wv.w;
    }
  }
  #pragma unroll
  for (int e = 0; e < NE; e++)
    #pragma unroll
    for (int o = 1; o < 16; o <<= 1)
      p[e] += __shfl_xor(p[e], o, 64);
  if (part == 0) {
    int e0 = 0;
    for (int e = 1; e < NE; e++) if (p[e] > p[e0]) e0 = e;   // first-occurrence argmax
    int e1 = -1;
    for (int e = 0; e < NE; e++) { if (e == e0) continue; if (e1 < 0 || p[e] > p[e1]) e1 = e; }
    float w0 = 1.f / (1.f + expf(p[e1] - p[e0]));            // softmax over top-2
    sel[tok * 2] = e0; sel[tok * 2 + 1] = e1;
    wts[tok * 2] = w0; wts[tok * 2 + 1] = 1.f - w0;
    atomicAdd(&lcnt[e0], 1); atomicAdd(&lcnt[e1], 1);
  }
  __syncthreads();
  if (tid < NE) atomicAdd(&counts[tid], lcnt[tid]);
}

__global__ void k_assign(const int* __restrict__ sel, const float* __restrict__ wts,
                         const int* __restrict__ counts, int* __restrict__ cur,
                         int* __restrict__ rowtok, float* __restrict__ roww) {
  int t = blockIdx.x * 256 + threadIdx.x;
  if (t >= Tt) return;
  int offs[NE];
  int a = 0;
  #pragma unroll
  for (int e = 0; e < NE; e++) { offs[e] = a; a += counts[e]; }
  #pragma unroll
  for (int k = 0; k < 2; k++) {
    int e = sel[t * 2 + k];
    int r = offs[e] + atomicAdd(&cur[e], 1);
    rowtok[r] = t; roww[r] = wts[t * 2 + k];
  }
}

// ---------------- GEMM helpers ----------------

__device__ __forceinline__ bool tile_map(const int* counts, int slot,
                                         int& rowbase, int& mval, int& e_out) {
  int acc = 0, base = 0, e = -1;
  for (int i = 0; i < NE; i++) {
    int c = counts[i];
    int nt = (c + BM - 1) / BM;
    if (e < 0 && slot < acc + nt) {
      int tl = slot - acc;
      e = i;
      rowbase = base + tl * BM;
      int rem = c - tl * BM;
      mval = rem < BM ? rem : BM;
    }
    acc += nt; base += c;
  }
  e_out = e;
  return e >= 0;
}

// LDS layout (BK=64): row = 128 B = 8 chunks of 16 B; logical chunk c of row r
// at slot c ^ (r&7). Staging lane l in an 8-row unit (row l>>3, slot l&7)
// fetches logical chunk (l&7)^(l>>3). Frag reads mirror the XOR -> each bank
// hit exactly 8x per b128 (conflict-free, verified round 2->3: SQ_LDS=0).

// 32x32x16 frag addressing: lane holds A[m=l&31][k=(l>>5)*8+j]; same for B^T
// rows. LDS addr: row*BK + ((kchunk ^ (row&7)) * 8), kchunk = kstep*2 + (l>>5).

// Merged GEMM1 (shared + expert): 128x64 tile, dual B, fused SwiGLU -> bf16.
__global__ __launch_bounds__(256, 3)
void k_gemm1(const u16* __restrict__ A,
             const u16* __restrict__ Sgt, const u16* __restrict__ Sut, u16* __restrict__ hs,
             const u16* __restrict__ Wgt, const u16* __restrict__ Wut, u16* __restrict__ h,
             const int* __restrict__ counts, const int* __restrict__ rowtok) {
  constexpr int KD = Hd;
  int bid = blockIdx.x;
  bool gather;
  const u16 *B1g, *B2g; u16* Ho;
  int NOUT, n, mt, rowbase, mval, eb = 0;
  if (bid < G1_SH) {
    gather = false; NOUT = ISd; B1g = Sgt; B2g = Sut; Ho = hs;
    int xcd = bid & 7, idx = bid >> 3;     // slabN = (ISd/BN1)/8 = 8
    n = xcd * 8 + (idx & 7); mt = idx >> 3;
    rowbase = mt * BM; mval = BM;
  } else {
    gather = true; NOUT = Id; Ho = h;
    int b2 = bid - G1_SH;
    int xcd = b2 & 7, idx = b2 >> 3;       // slabN = (Id/BN1)/8 = 4
    n = xcd * 4 + (idx & 3); mt = idx >> 2;
    if (!tile_map(counts, mt, rowbase, mval, eb)) return;
    size_t bmat = (size_t)eb * Id * KD;
    B1g = Wgt + bmat; B2g = Wut + bmat;
  }
  __shared__ u16 As[BM * BK], Bs1[BN1 * BK], Bs2[BN1 * BK];
  const int tid = threadIdx.x, w = tid >> 6, l = tid & 63;
  const int lr = l >> 3, cg = (l & 7) ^ lr;

  const u16* gp[8];
  u16* lp[8];
  if (w < 2) {                      // A rows w*64 .. +63
    #pragma unroll
    for (int j = 0; j < 8; j++) {
      int r = w * 64 + j * 8 + lr;
      int rr = (r < mval) ? r : 0;
      int arow = gather ? rowtok[rowbase + rr] : (rowbase + rr);
      gp[j] = A + (size_t)arow * KD + cg * 8;
      lp[j] = As + (w * 64 + j * 8) * BK;
    }
  } else if (w == 2) {              // B1 rows 0..63
    #pragma unroll
    for (int j = 0; j < 8; j++) {
      int r = j * 8 + lr;
      gp[j] = B1g + (size_t)(n * BN1 + r) * KD + cg * 8;
      lp[j] = Bs1 + (j * 8) * BK;
    }
  } else {                          // B2 rows 0..63
    #pragma unroll
    for (int j = 0; j < 8; j++) {
      int r = j * 8 + lr;
      gp[j] = B2g + (size_t)(n * BN1 + r) * KD + cg * 8;
      lp[j] = Bs2 + (j * 8) * BK;
    }
  }
  const int wm = w >> 1, wn = w & 1;
  const int l31 = l & 31, lh = l >> 5;
  f32x16 aG[2] = {}, aU[2] = {};

  for (int k0 = 0; k0 < KD; k0 += BK) {
    __syncthreads();
    #pragma unroll
    for (int j = 0; j < 8; j++) ld16(lp[j], gp[j] + k0);
    __syncthreads();
    #pragma unroll
    for (int ks = 0; ks < 4; ks++) {
      int kc = ks * 2 + lh;
      bf16x8 af[2], bf1, bf2;
      #pragma unroll
      for (int mi = 0; mi < 2; mi++) {
        int row = wm * 64 + mi * 32 + l31;
        af[mi] = *(const bf16x8*)(As + row * BK + ((kc ^ (row & 7)) * 8));
      }
      {
        int row = wn * 32 + l31;
        bf1 = *(const bf16x8*)(Bs1 + row * BK + ((kc ^ (row & 7)) * 8));
        bf2 = *(const bf16x8*)(Bs2 + row * BK + ((kc ^ (row & 7)) * 8));
      }
      #pragma unroll
      for (int mi = 0; mi < 2; mi++) {
        aG[mi] = __builtin_amdgcn_mfma_f32_32x32x16_bf16(af[mi], bf1, aG[mi], 0, 0, 0);
        aU[mi] = __builtin_amdgcn_mfma_f32_32x32x16_bf16(af[mi], bf2, aU[mi], 0, 0, 0);
      }
    }
  }
  // C/D: col = lane&31, row = (reg&3) + 8*(reg>>2) + 4*(lane>>5)
  #pragma unroll
  for (int mi = 0; mi < 2; mi++) {
    #pragma unroll
    for (int reg = 0; reg < 16; reg++) {
      int row = wm * 64 + mi * 32 + (reg & 3) + 8 * (reg >> 2) + 4 * lh;
      if (row < mval) {
        int c = n * BN1 + wn * 32 + l31;
        float g = aG[mi][reg], u = aU[mi][reg];
        Ho[(size_t)(rowbase + row) * NOUT + c] = f2bf(g / (1.f + __expf(-g)) * u);
      }
    }
  }
}

// Merged GEMM2 (shared ksplit-2 + expert): 128x128, atomic-add into zeroed out.
__global__ __launch_bounds__(256, 3)
void k_gemm2(const u16* __restrict__ hs, const u16* __restrict__ Sdt,
             const u16* __restrict__ h, const u16* __restrict__ Wdt,
             float* __restrict__ out,
             const int* __restrict__ counts, const int* __restrict__ rowtok,
             const float* __restrict__ roww) {
  int bid = blockIdx.x;
  bool gather;
  const u16 *A, *Bg;
  int n, rowbase, mval, eb = 0, kstart, KDrow;
  if (bid < G2_SH) {
    gather = false; KDrow = ISd;
    n = bid & 7;
    int idx = bid >> 3;
    int mt = idx & 31, kz = idx >> 5;      // MT=32, ksplit 2
    rowbase = mt * BM; mval = BM;
    kstart = kz * (ISd / 2);
    A = hs; Bg = Sdt;
  } else {
    gather = true; KDrow = Id;
    int b2 = bid - G2_SH;
    n = b2 & 7;
    int mt = b2 >> 3;
    if (!tile_map(counts, mt, rowbase, mval, eb)) return;
    kstart = 0;
    A = h; Bg = Wdt + (size_t)eb * Hd * Id;
  }
  __shared__ u16 As[BM * BK], Bs[BN * BK];
  const int tid = threadIdx.x, w = tid >> 6, l = tid & 63;
  const int lr = l >> 3, cg = (l & 7) ^ lr;

  const u16* gp[8];
  u16* lp[8];
  if (w < 2) {                      // A rows w*64 .. +63
    #pragma unroll
    for (int j = 0; j < 8; j++) {
      int r = w * 64 + j * 8 + lr;
      int rr = (r < mval) ? r : 0;
      gp[j] = A + (size_t)(rowbase + rr) * KDrow + cg * 8;
      lp[j] = As + (w * 64 + j * 8) * BK;
    }
  } else {                          // B rows (w-2)*64 .. +63
    #pragma unroll
    for (int j = 0; j < 8; j++) {
      int r = (w - 2) * 64 + j * 8 + lr;
      gp[j] = Bg + (size_t)(n * BN + r) * KDrow + cg * 8;
      lp[j] = Bs + ((w - 2) * 64 + j * 8) * BK;
    }
  }
  const int wm = w >> 1, wn = w & 1;
  const int l31 = l & 31, lh = l >> 5;
  f32x16 acc[2][2] = {};

  const int kend = kstart + 2048;   // shared: ISd/2; expert: Id — both 2048
  for (int k0 = kstart; k0 < kend; k0 += BK) {
    __syncthreads();
    #pragma unroll
    for (int j = 0; j < 8; j++) ld16(lp[j], gp[j] + k0);
    __syncthreads();
    #pragma unroll
    for (int ks = 0; ks < 4; ks++) {
      int kc = ks * 2 + lh;
      bf16x8 af[2], bf[2];
      #pragma unroll
      for (int mi = 0; mi < 2; mi++) {
        int row = wm * 64 + mi * 32 + l31;
        af[mi] = *(const bf16x8*)(As + row * BK + ((kc ^ (row & 7)) * 8));
      }
      #pragma unroll
      for (int ni = 0; ni < 2; ni++) {
        int row = wn * 64 + ni * 32 + l31;
        bf[ni] = *(const bf16x8*)(Bs + row * BK + ((kc ^ (row & 7)) * 8));
      }
      #pragma unroll
      for (int mi = 0; mi < 2; mi++)
        #pragma unroll
        for (int ni = 0; ni < 2; ni++)
          acc[mi][ni] = __builtin_amdgcn_mfma_f32_32x32x16_bf16(af[mi], bf[ni], acc[mi][ni], 0, 0, 0);
    }
  }
  #pragma unroll
  for (int mi = 0; mi < 2; mi++) {
    #pragma unroll
    for (int reg = 0; reg < 16; reg++) {
      int row = wm * 64 + mi * 32 + (reg & 3) + 8 * (reg >> 2) + 4 * lh;
      if (row < mval) {
        int grow = rowbase + row;
        float wt = 1.f;
        size_t o;
        if (gather) { o = (size_t)rowtok[grow] * Hd; wt = roww[grow]; }
        else o = (size_t)grow * Hd;
        #pragma unroll
        for (int ni = 0; ni < 2; ni++) {
          int c = n * BN + wn * 64 + ni * 32 + l31;
          atomicAdd(&out[o + c], wt * acc[mi][ni][reg]);
        }
      }
    }
  }
}

// ---------------- launch ----------------

extern "C" void kernel_launch(void* const* d_in, const int* in_sizes, int n_in,
                              void* d_out, int out_size, void* d_ws, size_t ws_size,
                              hipStream_t stream) {
  const float* x   = (const float*)d_in[0];
  const float* rwm = (const float*)d_in[1];
  const float* Wg  = (const float*)d_in[2];
  const float* Wu  = (const float*)d_in[3];
  const float* Wd  = (const float*)d_in[4];
  const float* Sg  = (const float*)d_in[5];
  const float* Su  = (const float*)d_in[6];
  const float* Sd  = (const float*)d_in[7];
  float* out = (float*)d_out;

  uint8_t* p = (uint8_t*)d_ws;
  auto take = [&](size_t bytes) { uint8_t* r = p; p += ((bytes + 255) & ~(size_t)255); return r; };
  u16* xb   = (u16*)take((size_t)Tt * Hd * 2);
  u16* Wgt  = (u16*)take((size_t)NE * Id * Hd * 2);   // [E][I][H]
  u16* Wut  = (u16*)take((size_t)NE * Id * Hd * 2);
  u16* Wdt  = (u16*)take((size_t)NE * Hd * Id * 2);   // [E][H][I]
  u16* Sgt  = (u16*)take((size_t)ISd * Hd * 2);       // [IS][H]
  u16* Sut  = (u16*)take((size_t)ISd * Hd * 2);
  u16* Sdt  = (u16*)take((size_t)Hd * ISd * 2);       // [H][IS]
  u16* hs   = (u16*)take((size_t)Tt * ISd * 2);       // shared intermediate
  u16* h    = (u16*)take((size_t)NR * Id * 2);        // expert intermediate
  int*   sel    = (int*)take(Tt * 2 * 4);
  float* wts    = (float*)take(Tt * 2 * 4);
  int*   rowtok = (int*)take(NR * 4);
  float* roww   = (float*)take(NR * 4);
  int*   ctrl   = (int*)take(2 * NE * 4);             // counts | cur
  int* counts = ctrl, *cur = ctrl + NE;

  hipMemsetAsync(ctrl, 0, 2 * NE * 4, stream);
  hipMemsetAsync(out, 0, (size_t)out_size * 4, stream);  // gemm2 accumulates atomically

  k_tcvt<<<15360, 256, 0, stream>>>(Wg, Wgt, Wu, Wut, Wd, Wdt, Sg, Sgt, Su, Sut, Sd, Sdt);
  k_router<<<Tt / 16, 256, 0, stream>>>(x, rwm, xb, sel, wts, counts);
  k_assign<<<Tt / 256, 256, 0, stream>>>(sel, wts, counts, cur, rowtok, roww);

  k_gemm1<<<G1_SH + G1_EX, 256, 0, stream>>>(xb, Sgt, Sut, hs, Wgt, Wut, h, counts, rowtok);
  k_gemm2<<<G2_SH + G2_EX, 256, 0, stream>>>(hs, Sdt, h, Wdt, out, counts, rowtok, roww);
}

// Round 6
// 570.505 us; speedup vs baseline: 1.1085x; 1.1085x over previous
//
#include <hip/hip_runtime.h>
#include <hip/hip_bf16.h>
#include <stdint.h>

// MoE: T=4096 tokens, H=1024, E=8 (top-2), I=2048, IS=4096. fp32 in/out.
// bf16 MFMA (16x16x32) pipeline: merged transpose dispatch, LDS-staged router
// (also emits bf16 x), LDS-aggregated assign, merged shared+expert BK=64 GEMMs
// with global_load_lds staging + XOR bank swizzle (verified conflict-free).

typedef __attribute__((ext_vector_type(8))) short bf16x8;   // MFMA A/B frag
typedef __attribute__((ext_vector_type(4))) float f32x4;    // MFMA C/D frag
typedef unsigned short u16;

static constexpr int Tt  = 4096;
static constexpr int Hd  = 1024;
static constexpr int NE  = 8;
static constexpr int Id  = 2048;
static constexpr int ISd = 4096;
static constexpr int NR  = Tt * 2;
static constexpr int BM = 128, BN = 128, BN1 = 64, BK = 64;
static constexpr int MAXT = NR / BM + NE;               // 72 worst-case expert M-tiles
static constexpr int G1_SH = (Tt / BM) * (ISd / BN1);   // 2048 shared gemm1 blocks
static constexpr int G1_EX = MAXT * (Id / BN1);         // 2304 expert gemm1 blocks
static constexpr int G2_SH = 8 * (Tt / BM) * 2;         // 512 shared gemm2 (ksplit 2)
static constexpr int G2_EX = 8 * MAXT;                  // 576 expert gemm2

__device__ __forceinline__ u16 f2bf(float f) {  // RNE float->bf16
  union { float f; uint32_t u; } v; v.f = f;
  uint32_t u = v.u;
  u += 0x7fffu + ((u >> 16) & 1u);
  return (u16)(u >> 16);
}

__device__ __forceinline__ void ld16(void* l, const void* g) {
  __builtin_amdgcn_global_load_lds((const __attribute__((address_space(1))) void*)g,
                                   (__attribute__((address_space(3))) void*)l, 16, 0, 0);
}

// ---------------- preprocessing ----------------

// ALL weight transposes in one dispatch. fp32 [z][K][N] -> bf16 [z][N][K], 64x64 tiles.
// Segments: Wg(8z), Wu(8z), Wd(8z), Sg, Su, Sd.
__global__ __launch_bounds__(256)
void k_tcvt(const float* __restrict__ s0, u16* __restrict__ d0,
            const float* __restrict__ s1, u16* __restrict__ d1,
            const float* __restrict__ s2, u16* __restrict__ d2,
            const float* __restrict__ s3, u16* __restrict__ d3,
            const float* __restrict__ s4, u16* __restrict__ d4,
            const float* __restrict__ s5, u16* __restrict__ d5) {
  constexpr int ST[6] = {0, 4096, 8192, 12288, 13312, 14336};
  constexpr int KS[6] = {1024, 1024, 2048, 1024, 1024, 4096};
  constexpr int NS[6] = {2048, 2048, 1024, 4096, 4096, 1024};
  int bid = blockIdx.x;
  int seg = 0;
  #pragma unroll
  for (int i = 1; i < 6; i++) if (bid >= ST[i]) seg = i;
  const float* S; u16* D;
  switch (seg) {
    case 0: S = s0; D = d0; break;
    case 1: S = s1; D = d1; break;
    case 2: S = s2; D = d2; break;
    case 3: S = s3; D = d3; break;
    case 4: S = s4; D = d4; break;
    default: S = s5; D = d5; break;
  }
  int K = KS[seg], N = NS[seg];
  int lb = bid - ST[seg];
  int perz = (N >> 6) * (K >> 6);
  int z = lb / perz, r = lb - z * perz;
  int bx = r % (N >> 6), by = r / (N >> 6);
  S += (size_t)z * K * N; D += (size_t)z * K * N;
  int n0 = bx * 64, k0 = by * 64;

  __shared__ float sm[64][65];
  int tid = threadIdx.x;
  int rr = tid >> 4, cc = (tid & 15) * 4;
  #pragma unroll
  for (int i = 0; i < 4; i++) {
    float4 v = *(const float4*)&S[(size_t)(k0 + i * 16 + rr) * N + n0 + cc];
    sm[i * 16 + rr][cc] = v.x; sm[i * 16 + rr][cc + 1] = v.y;
    sm[i * 16 + rr][cc + 2] = v.z; sm[i * 16 + rr][cc + 3] = v.w;
  }
  __syncthreads();
  int nn = tid >> 3, kc = (tid & 7) * 8;
  #pragma unroll
  for (int i = 0; i < 2; i++) {
    int n = i * 32 + nn;
    union { u16 h[8]; uint4 v; } o;
    #pragma unroll
    for (int t = 0; t < 8; t++) o.h[t] = f2bf(sm[kc + t][n]);
    *(uint4*)&D[(size_t)(n0 + n) * K + k0 + kc] = o.v;
  }
}

// ---------------- router (also casts x -> bf16 xb) ----------------
// 256 blocks x 256 thr. rwm (32 KB) in LDS. 16 thr/token, interleaved float4.

__global__ __launch_bounds__(256)
void k_router(const float* __restrict__ x, const float* __restrict__ rwm,
              u16* __restrict__ xb,
              int* __restrict__ sel, float* __restrict__ wts,
              int* __restrict__ counts) {
  __shared__ float w[NE * Hd];
  __shared__ int lcnt[NE];
  int tid = threadIdx.x;
  if (tid < NE) lcnt[tid] = 0;
  #pragma unroll
  for (int i = 0; i < 8; i++) {
    int idx = (i * 256 + tid) * 4;
    *(float4*)&w[idx] = *(const float4*)&rwm[idx];
  }
  __syncthreads();
  int tok = blockIdx.x * 16 + (tid >> 4);
  int part = tid & 15;
  const float* xt = x + (size_t)tok * Hd;
  u16* xbt = xb + (size_t)tok * Hd;
  float p[NE] = {};
  #pragma unroll
  for (int j = 0; j < 16; j++) {
    int off = j * 64 + part * 4;
    float4 v = *(const float4*)&xt[off];
    ushort4 o;
    o.x = f2bf(v.x); o.y = f2bf(v.y); o.z = f2bf(v.z); o.w = f2bf(v.w);
    *(ushort4*)&xbt[off] = o;
    #pragma unroll
    for (int e = 0; e < NE; e++) {
      float4 wv = *(const float4*)&w[e * Hd + off];
      p[e] += v.x * wv.x + v.y * wv.y + v.z * wv.z + v.w * wv.w;
    }
  }
  #pragma unroll
  for (int e = 0; e < NE; e++)
    #pragma unroll
    for (int o = 1; o < 16; o <<= 1)
      p[e] += __shfl_xor(p[e], o, 64);
  if (part == 0) {
    int e0 = 0;
    for (int e = 1; e < NE; e++) if (p[e] > p[e0]) e0 = e;   // first-occurrence argmax
    int e1 = -1;
    for (int e = 0; e < NE; e++) { if (e == e0) continue; if (e1 < 0 || p[e] > p[e1]) e1 = e; }
    float w0 = 1.f / (1.f + expf(p[e1] - p[e0]));            // softmax over top-2
    sel[tok * 2] = e0; sel[tok * 2 + 1] = e1;
    wts[tok * 2] = w0; wts[tok * 2 + 1] = 1.f - w0;
    atomicAdd(&lcnt[e0], 1); atomicAdd(&lcnt[e1], 1);
  }
  __syncthreads();
  if (tid < NE) atomicAdd(&counts[tid], lcnt[tid]);
}

// LDS-aggregated assign: per-block LDS histogram ranks, then 8 global atomics
// per block to reserve ranges (128 total vs 8192 same-address atomics before).
__global__ __launch_bounds__(256)
void k_assign(const int* __restrict__ sel, const float* __restrict__ wts,
              const int* __restrict__ counts, int* __restrict__ cur,
              int* __restrict__ rowtok, float* __restrict__ roww) {
  __shared__ int lcnt[NE], lbase[NE];
  int tid = threadIdx.x;
  if (tid < NE) lcnt[tid] = 0;
  __syncthreads();
  int t = blockIdx.x * 256 + tid;
  int e0 = sel[t * 2], e1 = sel[t * 2 + 1];
  int r0 = atomicAdd(&lcnt[e0], 1);      // LDS atomic: cheap
  int r1 = atomicAdd(&lcnt[e1], 1);
  __syncthreads();
  if (tid < NE) lbase[tid] = atomicAdd(&cur[tid], lcnt[tid]);
  __syncthreads();
  int offs[NE];
  int a = 0;
  #pragma unroll
  for (int e = 0; e < NE; e++) { offs[e] = a; a += counts[e]; }
  int p0 = offs[e0] + lbase[e0] + r0;
  rowtok[p0] = t; roww[p0] = wts[t * 2];
  int p1 = offs[e1] + lbase[e1] + r1;
  rowtok[p1] = t; roww[p1] = wts[t * 2 + 1];
}

// ---------------- GEMM helpers ----------------

__device__ __forceinline__ bool tile_map(const int* counts, int slot,
                                         int& rowbase, int& mval, int& e_out) {
  int acc = 0, base = 0, e = -1;
  for (int i = 0; i < NE; i++) {
    int c = counts[i];
    int nt = (c + BM - 1) / BM;
    if (e < 0 && slot < acc + nt) {
      int tl = slot - acc;
      e = i;
      rowbase = base + tl * BM;
      int rem = c - tl * BM;
      mval = rem < BM ? rem : BM;
    }
    acc += nt; base += c;
  }
  e_out = e;
  return e >= 0;
}

// LDS layout (BK=64): row = 128 B = 8 chunks of 16 B; logical chunk c of row r
// at slot c ^ (r&7). Staging lane l in an 8-row unit (row l>>3, slot l&7)
// fetches logical chunk (l&7)^(l>>3). 16x16 frag reads (q = l>>4) mirror the
// XOR -> measured SQ_LDS_BANK_CONFLICT = 0. (32x32 frag pattern conflicted —
// 1.7e7 cycles, round 5 — do NOT switch without re-measuring.)

// Merged GEMM1 (shared + expert): 128x64 tile, dual B, fused SwiGLU -> bf16.
__global__ __launch_bounds__(256, 3)
void k_gemm1(const u16* __restrict__ A,
             const u16* __restrict__ Sgt, const u16* __restrict__ Sut, u16* __restrict__ hs,
             const u16* __restrict__ Wgt, const u16* __restrict__ Wut, u16* __restrict__ h,
             const int* __restrict__ counts, const int* __restrict__ rowtok) {
  constexpr int KD = Hd;
  int bid = blockIdx.x;
  bool gather;
  const u16 *B1g, *B2g; u16* Ho;
  int NOUT, n, mt, rowbase, mval, eb = 0;
  if (bid < G1_SH) {
    gather = false; NOUT = ISd; B1g = Sgt; B2g = Sut; Ho = hs;
    int xcd = bid & 7, idx = bid >> 3;     // slabN = (ISd/BN1)/8 = 8
    n = xcd * 8 + (idx & 7); mt = idx >> 3;
    rowbase = mt * BM; mval = BM;
  } else {
    gather = true; NOUT = Id; Ho = h;
    int b2 = bid - G1_SH;
    int xcd = b2 & 7, idx = b2 >> 3;       // slabN = (Id/BN1)/8 = 4
    n = xcd * 4 + (idx & 3); mt = idx >> 2;
    if (!tile_map(counts, mt, rowbase, mval, eb)) return;
    size_t bmat = (size_t)eb * Id * KD;
    B1g = Wgt + bmat; B2g = Wut + bmat;
  }
  __shared__ u16 As[BM * BK], Bs1[BN1 * BK], Bs2[BN1 * BK];
  const int tid = threadIdx.x, w = tid >> 6, l = tid & 63;
  const int lr = l >> 3, cg = (l & 7) ^ lr;

  const u16* gp[8];
  u16* lp[8];
  if (w < 2) {                      // A rows w*64 .. +63
    #pragma unroll
    for (int j = 0; j < 8; j++) {
      int r = w * 64 + j * 8 + lr;
      int rr = (r < mval) ? r : 0;
      int arow = gather ? rowtok[rowbase + rr] : (rowbase + rr);
      gp[j] = A + (size_t)arow * KD + cg * 8;
      lp[j] = As + (w * 64 + j * 8) * BK;
    }
  } else if (w == 2) {              // B1 rows 0..63
    #pragma unroll
    for (int j = 0; j < 8; j++) {
      int r = j * 8 + lr;
      gp[j] = B1g + (size_t)(n * BN1 + r) * KD + cg * 8;
      lp[j] = Bs1 + (j * 8) * BK;
    }
  } else {                          // B2 rows 0..63
    #pragma unroll
    for (int j = 0; j < 8; j++) {
      int r = j * 8 + lr;
      gp[j] = B2g + (size_t)(n * BN1 + r) * KD + cg * 8;
      lp[j] = Bs2 + (j * 8) * BK;
    }
  }
  const int wm = w >> 1, wn = w & 1, q = l >> 4, rl = l & 15;
  const int r7 = rl & 7;
  f32x4 aG[4][2] = {}, aU[4][2] = {};

  for (int k0 = 0; k0 < KD; k0 += BK) {
    __syncthreads();
    #pragma unroll
    for (int j = 0; j < 8; j++) ld16(lp[j], gp[j] + k0);
    __syncthreads();
    #pragma unroll
    for (int kk = 0; kk < 2; kk++) {
      bf16x8 af[4], bf1[2], bf2[2];
      #pragma unroll
      for (int i = 0; i < 4; i++)
        af[i] = *(const bf16x8*)(As + (wm * 64 + i * 16 + rl) * BK + ((kk * 4 + q) ^ r7) * 8);
      #pragma unroll
      for (int i = 0; i < 2; i++) {
        bf1[i] = *(const bf16x8*)(Bs1 + (wn * 32 + i * 16 + rl) * BK + ((kk * 4 + q) ^ r7) * 8);
        bf2[i] = *(const bf16x8*)(Bs2 + (wn * 32 + i * 16 + rl) * BK + ((kk * 4 + q) ^ r7) * 8);
      }
      #pragma unroll
      for (int a = 0; a < 4; a++)
        #pragma unroll
        for (int b = 0; b < 2; b++) {
          aG[a][b] = __builtin_amdgcn_mfma_f32_16x16x32_bf16(af[a], bf1[b], aG[a][b], 0, 0, 0);
          aU[a][b] = __builtin_amdgcn_mfma_f32_16x16x32_bf16(af[a], bf2[b], aU[a][b], 0, 0, 0);
        }
    }
  }
  #pragma unroll
  for (int a = 0; a < 4; a++) {
    #pragma unroll
    for (int r = 0; r < 4; r++) {
      int row = wm * 64 + a * 16 + q * 4 + r;
      if (row < mval) {
        size_t ro = (size_t)(rowbase + row) * NOUT;
        #pragma unroll
        for (int b = 0; b < 2; b++) {
          int c = n * BN1 + wn * 32 + b * 16 + rl;
          float g = aG[a][b][r], u = aU[a][b][r];
          Ho[ro + c] = f2bf(g / (1.f + __expf(-g)) * u);
        }
      }
    }
  }
}

// Merged GEMM2 (shared ksplit-2 + expert): 128x128, atomic-add into zeroed out.
__global__ __launch_bounds__(256, 3)
void k_gemm2(const u16* __restrict__ hs, const u16* __restrict__ Sdt,
             const u16* __restrict__ h, const u16* __restrict__ Wdt,
             float* __restrict__ out,
             const int* __restrict__ counts, const int* __restrict__ rowtok,
             const float* __restrict__ roww) {
  int bid = blockIdx.x;
  bool gather;
  const u16 *A, *Bg;
  int n, rowbase, mval, eb = 0, kstart, KDrow;
  if (bid < G2_SH) {
    gather = false; KDrow = ISd;
    n = bid & 7;
    int idx = bid >> 3;
    int mt = idx & 31, kz = idx >> 5;      // MT=32, ksplit 2
    rowbase = mt * BM; mval = BM;
    kstart = kz * (ISd / 2);
    A = hs; Bg = Sdt;
  } else {
    gather = true; KDrow = Id;
    int b2 = bid - G2_SH;
    n = b2 & 7;
    int mt = b2 >> 3;
    if (!tile_map(counts, mt, rowbase, mval, eb)) return;
    kstart = 0;
    A = h; Bg = Wdt + (size_t)eb * Hd * Id;
  }
  __shared__ u16 As[BM * BK], Bs[BN * BK];
  const int tid = threadIdx.x, w = tid >> 6, l = tid & 63;
  const int lr = l >> 3, cg = (l & 7) ^ lr;

  const u16* gp[8];
  u16* lp[8];
  if (w < 2) {                      // A rows w*64 .. +63
    #pragma unroll
    for (int j = 0; j < 8; j++) {
      int r = w * 64 + j * 8 + lr;
      int rr = (r < mval) ? r : 0;
      gp[j] = A + (size_t)(rowbase + rr) * KDrow + cg * 8;
      lp[j] = As + (w * 64 + j * 8) * BK;
    }
  } else {                          // B rows (w-2)*64 .. +63
    #pragma unroll
    for (int j = 0; j < 8; j++) {
      int r = (w - 2) * 64 + j * 8 + lr;
      gp[j] = Bg + (size_t)(n * BN + r) * KDrow + cg * 8;
      lp[j] = Bs + ((w - 2) * 64 + j * 8) * BK;
    }
  }
  const int wm = w >> 1, wn = w & 1, q = l >> 4, rl = l & 15;
  const int r7 = rl & 7;
  f32x4 acc[4][4] = {};

  const int kend = kstart + 2048;   // shared: ISd/2; expert: Id — both 2048
  for (int k0 = kstart; k0 < kend; k0 += BK) {
    __syncthreads();
    #pragma unroll
    for (int j = 0; j < 8; j++) ld16(lp[j], gp[j] + k0);
    __syncthreads();
    #pragma unroll
    for (int kk = 0; kk < 2; kk++) {
      bf16x8 af[4], bf[4];
      #pragma unroll
      for (int i = 0; i < 4; i++) {
        af[i] = *(const bf16x8*)(As + (wm * 64 + i * 16 + rl) * BK + ((kk * 4 + q) ^ r7) * 8);
        bf[i] = *(const bf16x8*)(Bs + (wn * 64 + i * 16 + rl) * BK + ((kk * 4 + q) ^ r7) * 8);
      }
      #pragma unroll
      for (int a = 0; a < 4; a++)
        #pragma unroll
        for (int b = 0; b < 4; b++)
          acc[a][b] = __builtin_amdgcn_mfma_f32_16x16x32_bf16(af[a], bf[b], acc[a][b], 0, 0, 0);
    }
  }
  #pragma unroll
  for (int a = 0; a < 4; a++) {
    #pragma unroll
    for (int r = 0; r < 4; r++) {
      int row = wm * 64 + a * 16 + q * 4 + r;
      if (row < mval) {
        int grow = rowbase + row;
        float wt = 1.f;
        size_t o;
        if (gather) { o = (size_t)rowtok[grow] * Hd; wt = roww[grow]; }
        else o = (size_t)grow * Hd;
        #pragma unroll
        for (int b = 0; b < 4; b++) {
          int c = n * BN + wn * 64 + b * 16 + rl;
          atomicAdd(&out[o + c], wt * acc[a][b][r]);
        }
      }
    }
  }
}

// ---------------- launch ----------------

extern "C" void kernel_launch(void* const* d_in, const int* in_sizes, int n_in,
                              void* d_out, int out_size, void* d_ws, size_t ws_size,
                              hipStream_t stream) {
  const float* x   = (const float*)d_in[0];
  const float* rwm = (const float*)d_in[1];
  const float* Wg  = (const float*)d_in[2];
  const float* Wu  = (const float*)d_in[3];
  const float* Wd  = (const float*)d_in[4];
  const float* Sg  = (const float*)d_in[5];
  const float* Su  = (const float*)d_in[6];
  const float* Sd  = (const float*)d_in[7];
  float* out = (float*)d_out;

  uint8_t* p = (uint8_t*)d_ws;
  auto take = [&](size_t bytes) { uint8_t* r = p; p += ((bytes + 255) & ~(size_t)255); return r; };
  u16* xb   = (u16*)take((size_t)Tt * Hd * 2);
  u16* Wgt  = (u16*)take((size_t)NE * Id * Hd * 2);   // [E][I][H]
  u16* Wut  = (u16*)take((size_t)NE * Id * Hd * 2);
  u16* Wdt  = (u16*)take((size_t)NE * Hd * Id * 2);   // [E][H][I]
  u16* Sgt  = (u16*)take((size_t)ISd * Hd * 2);       // [IS][H]
  u16* Sut  = (u16*)take((size_t)ISd * Hd * 2);
  u16* Sdt  = (u16*)take((size_t)Hd * ISd * 2);       // [H][IS]
  u16* hs   = (u16*)take((size_t)Tt * ISd * 2);       // shared intermediate
  u16* h    = (u16*)take((size_t)NR * Id * 2);        // expert intermediate
  int*   sel    = (int*)take(Tt * 2 * 4);
  float* wts    = (float*)take(Tt * 2 * 4);
  int*   rowtok = (int*)take(NR * 4);
  float* roww   = (float*)take(NR * 4);
  int*   ctrl   = (int*)take(2 * NE * 4);             // counts | cur
  int* counts = ctrl, *cur = ctrl + NE;

  hipMemsetAsync(ctrl, 0, 2 * NE * 4, stream);
  hipMemsetAsync(out, 0, (size_t)out_size * 4, stream);  // gemm2 accumulates atomically

  k_tcvt<<<15360, 256, 0, stream>>>(Wg, Wgt, Wu, Wut, Wd, Wdt, Sg, Sgt, Su, Sut, Sd, Sdt);
  k_router<<<Tt / 16, 256, 0, stream>>>(x, rwm, xb, sel, wts, counts);
  k_assign<<<Tt / 256, 256, 0, stream>>>(sel, wts, counts, cur, rowtok, roww);

  k_gemm1<<<G1_SH + G1_EX, 256, 0, stream>>>(xb, Sgt, Sut, hs, Wgt, Wut, h, counts, rowtok);
  k_gemm2<<<G2_SH + G2_EX, 256, 0, stream>>>(hs, Sdt, h, Wdt, out, counts, rowtok, roww);
}